// Round 1
// 15656.351 us; speedup vs baseline: 1.0797x; 1.0797x over previous
//
#include <hip/hip_runtime.h>
#include <hip/hip_bf16.h>
#include <hip/hip_fp16.h>
#include <stdint.h>

#define BB 64
#define TT 512
#define II 256
#define HH 1024
#define G4 4096

typedef unsigned short u16;
typedef __attribute__((ext_vector_type(8))) _Float16 h8;
typedef __attribute__((ext_vector_type(4))) float f32x4;

__device__ __forceinline__ u16 f2h(float x){
  _Float16 h = (_Float16)x;
  return __builtin_bit_cast(u16, h);
}
__device__ __forceinline__ float sigm(float x){ return 1.0f/(1.0f + __expf(-x)); }
__device__ __forceinline__ float tanh_f(float x){ return 1.0f - 2.0f/(1.0f + __expf(2.0f*x)); }

// agent-scope (cross-XCD coherent) 16B load as two relaxed 8B atomics
__device__ __forceinline__ h8 aload16(const u16* p){
  union { unsigned long long v[2]; h8 h; } u;
  const unsigned long long* q = (const unsigned long long*)p;
  u.v[0] = __hip_atomic_load(q,     __ATOMIC_RELAXED, __HIP_MEMORY_SCOPE_AGENT);
  u.v[1] = __hip_atomic_load(q + 1, __ATOMIC_RELAXED, __HIP_MEMORY_SCOPE_AGENT);
  return u.h;
}

// ---------------- prep kernels ----------------
__global__ void bias_comb_kernel(const float* __restrict__ a, const float* __restrict__ b,
                                 float* __restrict__ o, int n){
  int i = blockIdx.x*blockDim.x + threadIdx.x;
  if (i < n) o[i] = a[i] + b[i];
}

// x: [B][T][I] fp32 -> xb: [(t*B+b)][I] fp16
__global__ void xconv_kernel(const float* __restrict__ x, u16* __restrict__ xb){
  int m = blockIdx.x;            // t*BB + b
  int t = m >> 6, b = m & 63;
  const float4* src = (const float4*)(x + ((size_t)b*TT + t)*II);
  float4 v = src[threadIdx.x];   // 64 threads * 4 = 256 = II
  ushort4 o; o.x=f2h(v.x); o.y=f2h(v.y); o.z=f2h(v.z); o.w=f2h(v.w);
  ((ushort4*)(xb + (size_t)m*II))[threadIdx.x] = o;
}

// Concat-K weight swizzle into MFMA B-frag order (fp32 -> fp16).
__global__ void wswz_kernel(const float* __restrict__ Wa, int Ka,
                            const float* __restrict__ Wb, int Kb,
                            u16* __restrict__ dst, int KS){
  int s8 = blockIdx.x*blockDim.x + threadIdx.x;
  int lane = s8 & 63;
  int g    = (s8 >> 6) & 3;
  int rest = s8 >> 8;
  int ks   = rest % KS;
  int jg   = rest / KS;
  if (jg >= 64) return;
  int id = lane & 15, quad = lane >> 4;
  int n = g*HH + jg*16 + id;
  int k = ks*32 + quad*8;
  const float* src = (k < Ka) ? (Wa + (size_t)n*Ka + k) : (Wb + (size_t)n*Kb + (k - Ka));
  float4 v0 = ((const float4*)src)[0];
  float4 v1 = ((const float4*)src)[1];
  ushort4 o0; o0.x=f2h(v0.x); o0.y=f2h(v0.y); o0.z=f2h(v0.z); o0.w=f2h(v0.w);
  ushort4 o1; o1.x=f2h(v1.x); o1.y=f2h(v1.y); o1.z=f2h(v1.z); o1.w=f2h(v1.w);
  u16* d = dst + (size_t)s8*8;
  ((ushort4*)d)[0] = o0;
  ((ushort4*)d)[1] = o1;
}

#define MF4(a, wp, A) \
  A[0] = __builtin_amdgcn_mfma_f32_16x16x32_f16((a), *(const h8*)((wp)       ), A[0], 0,0,0); \
  A[1] = __builtin_amdgcn_mfma_f32_16x16x32_f16((a), *(const h8*)((wp) +  512), A[1], 0,0,0); \
  A[2] = __builtin_amdgcn_mfma_f32_16x16x32_f16((a), *(const h8*)((wp) + 1024), A[2], 0,0,0); \
  A[3] = __builtin_amdgcn_mfma_f32_16x16x32_f16((a), *(const h8*)((wp) + 1536), A[3], 0,0,0);

// ---------------- fused 2-layer persistent LSTM ----------------
// 128 blocks x 256 threads. blocks 0..63: layer0 (K = 256 x + 1024 h0);
// blocks 64..127: layer1 (K = 1024 y0 + 1024 h1), lagging one epoch.
// Grid barrier: DISTRIBUTED arrive/release. Each block stores its epoch to its
// own 128B-padded slot (no RMW, no shared line); block 0's lanes 0..127 poll
// one slot each; release broadcast via 8 replicated padded words.
__launch_bounds__(256, 1)
__global__ void lstm_fused_kernel(const u16* __restrict__ xb,
                                  const u16* __restrict__ Wsw0,
                                  const u16* __restrict__ Wsw1,
                                  const float* __restrict__ bias0,
                                  const float* __restrict__ bias1,
                                  u16* __restrict__ h0buf,   // 2 slots [64][1024] fp16
                                  u16* __restrict__ h1buf,   // 2 slots
                                  float* __restrict__ hfin,  // [2][64][1024] fp32
                                  int* __restrict__ arr,     // 128 slots, stride 32 ints
                                  int* __restrict__ rel){    // 8 slots, stride 32 ints
  __shared__ float Gs[64*68];        // gate-rows(4g x 16j) x batches(64+pad)
  const int blk = blockIdx.x;
  const int layer = blk >> 6;
  const int jg = blk & 63;
  const int tid = threadIdx.x, wave = tid >> 6, lane = tid & 63;
  const int id = lane & 15, quad = lane >> 4;
  const int KS = layer ? 64 : 40;
  const u16* Wblk = (layer ? Wsw1 : Wsw0) + (size_t)jg * KS * 2048;
  const int ab = wave*16 + id;       // A-row (batch) this lane loads
  const int cb = tid >> 2, jq = tid & 3;  // cell phase: batch cb, j-quad jq
  const int j0 = jg * 16;
  const float* Bp = layer ? bias1 : bias0;
  float bs[4][4];
  #pragma unroll
  for (int g = 0; g < 4; ++g)
    #pragma unroll
    for (int jj = 0; jj < 4; ++jj)
      bs[g][jj] = Bp[g*HH + j0 + jq*4 + jj];
  float c4[4] = {0.f, 0.f, 0.f, 0.f};

  for (int e = 0; e <= 512; ++e){
    const bool active = layer ? (e >= 1) : (e < 512);
    if (active){
      const int t = layer ? (e - 1) : e;   // this layer's timestep
      const u16* hA0 = h0buf + ((size_t)(e & 1) << 16);        // h0[t-1] / y0[t]
      const u16* hA1 = h1buf + ((size_t)((e + 1) & 1) << 16);  // h1[t-1] (layer1)
      u16* hout = layer ? (h1buf + ((size_t)(e & 1) << 16))
                        : (h0buf + ((size_t)((e + 1) & 1) << 16));
      f32x4 accA[4] = {}, accB[4] = {};
      if (layer == 0){
        const u16* xrow = xb + ((size_t)(t*64 + ab) << 8);
        #pragma unroll
        for (int ks = 0; ks < 8; ++ks){
          h8 a = *(const h8*)(xrow + ks*32 + quad*8);
          MF4(a, Wblk + (size_t)ks*2048 + lane*8, accA);
        }
        const u16* hrow = hA0 + ((size_t)ab << 10) + quad*8;
        #pragma unroll 8
        for (int ks = 0; ks < 16; ++ks){
          h8 a0 = aload16(hrow + ks*32);
          h8 a1 = aload16(hrow + (ks + 16)*32);
          MF4(a0, Wblk + (size_t)(8 + ks)*2048 + lane*8, accA);
          MF4(a1, Wblk + (size_t)(24 + ks)*2048 + lane*8, accB);
        }
      } else {
        const u16* h0row = hA0 + ((size_t)ab << 10) + quad*8;
        const u16* h1row = hA1 + ((size_t)ab << 10) + quad*8;
        #pragma unroll 8
        for (int ks = 0; ks < 32; ++ks){
          h8 a0 = aload16(h0row + ks*32);
          h8 a1 = aload16(h1row + ks*32);
          MF4(a0, Wblk + (size_t)ks*2048 + lane*8, accA);
          MF4(a1, Wblk + (size_t)(ks + 32)*2048 + lane*8, accB);
        }
      }
      // exchange: D lane(id,quad),reg r -> batch = wave*16 + quad*4 + r, gate-row = g*16 + id
      #pragma unroll
      for (int g = 0; g < 4; ++g){
        f32x4 s = accA[g] + accB[g];
        *(f32x4*)&Gs[(size_t)(g*16 + id)*68 + wave*16 + quad*4] = s;
      }
      __syncthreads();
      // cell phase: 4 cells (batch cb, j = j0 + jq*4 + jj)
      ushort4 hb; float4 hf;
      #pragma unroll
      for (int jj = 0; jj < 4; ++jj){
        int jl = jq*4 + jj;
        float pi = Gs[(     jl)*68 + cb] + bs[0][jj];
        float pf = Gs[(16 + jl)*68 + cb] + bs[1][jj];
        float pg = Gs[(32 + jl)*68 + cb] + bs[2][jj];
        float po = Gs[(48 + jl)*68 + cb] + bs[3][jj];
        float iv = sigm(pi), fv = sigm(pf), gv = tanh_f(pg), ov = sigm(po);
        float c = fv*c4[jj] + iv*gv;
        c4[jj] = c;
        float h = ov * tanh_f(c);
        (&hf.x)[jj] = h;
        ((u16*)&hb)[jj] = f2h(h);
      }
      union { ushort4 s; unsigned long long v; } pk; pk.s = hb;
      __hip_atomic_store((unsigned long long*)&hout[(size_t)cb*HH + j0 + jq*4],
                         pk.v, __ATOMIC_RELAXED, __HIP_MEMORY_SCOPE_AGENT);
      if (t == TT - 1)
        *(float4*)&hfin[(size_t)layer*(BB*HH) + (size_t)cb*HH + j0 + jq*4] = hf;
    }
    if (e < 512){
      __syncthreads();   // drains vmcnt: all h-stores ack'd at coherence point
      const int next = e + 1;
      if (tid == 0)
        __hip_atomic_store(arr + blk*32, next, __ATOMIC_RELAXED, __HIP_MEMORY_SCOPE_AGENT);
      if (blk == 0){
        // aggregator: each of 128 lanes polls one distinct padded slot
        if (tid < 128){
          while (__hip_atomic_load(arr + tid*32, __ATOMIC_RELAXED, __HIP_MEMORY_SCOPE_AGENT) < next)
            __builtin_amdgcn_s_sleep(2);
        }
        __syncthreads();
        if (tid < 8)
          __hip_atomic_store(rel + tid*32, next, __ATOMIC_RELAXED, __HIP_MEMORY_SCOPE_AGENT);
        // block 0 proceeds immediately: it has observed all arrivals itself
      } else {
        if (tid == 0){
          while (__hip_atomic_load(rel + (blk & 7)*32, __ATOMIC_RELAXED, __HIP_MEMORY_SCOPE_AGENT) < next)
            __builtin_amdgcn_s_sleep(2);
        }
        __syncthreads();   // no loads of epoch e+1 can be hoisted above this
      }
    }
  }
}

// ---------------- FC head ----------------
__global__ void fc_kernel(const float* __restrict__ hfin, const float* __restrict__ fcw,
                          const float* __restrict__ fcb, float* __restrict__ out){
  int row = blockIdx.x;          // 0..127  (0..63 layer0 hT, 64..127 layer1 hT)
  int lane = threadIdx.x;        // 64
  const float* h = hfin + (size_t)row*HH;
  float a0 = 0.f, a1 = 0.f;
  for (int j = lane; j < HH; j += 64){
    float v = h[j]; v = v > 0.f ? v : 0.f;
    a0 += v * fcw[j];
    a1 += v * fcw[HH + j];
  }
  for (int off = 32; off; off >>= 1){ a0 += __shfl_down(a0, off); a1 += __shfl_down(a1, off); }
  if (lane == 0){
    out[row*2 + 0] = 1.f/(1.f + __expf(-(a0 + fcb[0])));
    out[row*2 + 1] = 1.f/(1.f + __expf(-(a1 + fcb[1])));
  }
}

// ---------------- launch ----------------
extern "C" void kernel_launch(void* const* d_in, const int* in_sizes, int n_in,
                              void* d_out, int out_size, void* d_ws, size_t ws_size,
                              hipStream_t stream){
  (void)in_sizes; (void)n_in; (void)out_size; (void)ws_size;
  const float* x    = (const float*)d_in[0];
  const float* Wih0 = (const float*)d_in[1];
  const float* Whh0 = (const float*)d_in[2];
  const float* bih0 = (const float*)d_in[3];
  const float* bhh0 = (const float*)d_in[4];
  const float* Wih1 = (const float*)d_in[5];
  const float* Whh1 = (const float*)d_in[6];
  const float* bih1 = (const float*)d_in[7];
  const float* bhh1 = (const float*)d_in[8];
  const float* fcw  = (const float*)d_in[9];
  const float* fcb  = (const float*)d_in[10];

  char* w = (char*)d_ws;
  size_t off = 0;
  auto take = [&](size_t bytes)->char*{
    char* p = w + off; off += (bytes + 255) & ~(size_t)255; return p;
  };
  u16*   xb    = (u16*)  take((size_t)TT*BB*II*2);       // 16 MB
  u16*   wsw0  = (u16*)  take((size_t)G4*1280*2);        // 10 MB  (K=256+1024)
  u16*   wsw1  = (u16*)  take((size_t)G4*2048*2);        // 16 MB  (K=1024+1024)
  float* bias0 = (float*)take(G4*4);
  float* bias1 = (float*)take(G4*4);
  u16*   h0buf = (u16*)  take(2*(size_t)BB*HH*2);        // 256 KB ping-pong
  u16*   h1buf = (u16*)  take(2*(size_t)BB*HH*2);
  float* hfin  = (float*)take(2*(size_t)BB*HH*4);        // 512 KB
  int*   arr   = (int*)  take(128*128);                  // 128 slots x 128B
  int*   rel   = (int*)  take(8*128);                    // 8 replicated release words

  hipMemsetAsync(h0buf, 0, 2*(size_t)BB*HH*2, stream);
  hipMemsetAsync(h1buf, 0, 2*(size_t)BB*HH*2, stream);
  hipMemsetAsync(arr,   0, 128*128, stream);
  hipMemsetAsync(rel,   0, 8*128, stream);

  bias_comb_kernel<<<16, 256, 0, stream>>>(bih0, bhh0, bias0, G4);
  bias_comb_kernel<<<16, 256, 0, stream>>>(bih1, bhh1, bias1, G4);
  xconv_kernel<<<TT*BB, 64, 0, stream>>>(x, xb);
  // L0: K=1280 (KS=40): 64*40*4*64/256 = 2560 blocks; L1: K=2048 (KS=64): 4096 blocks
  wswz_kernel<<<2560, 256, 0, stream>>>(Wih0, II, Whh0, HH, wsw0, 40);
  wswz_kernel<<<4096, 256, 0, stream>>>(Wih1, HH, Whh1, HH, wsw1, 64);

  lstm_fused_kernel<<<128, 256, 0, stream>>>(xb, wsw0, wsw1, bias0, bias1,
                                             h0buf, h1buf, hfin, arr, rel);
  fc_kernel<<<2*BB, 64, 0, stream>>>(hfin, fcw, fcb, (float*)d_out);
}

// Round 2
// 15228.088 us; speedup vs baseline: 1.1101x; 1.0281x over previous
//
#include <hip/hip_runtime.h>
#include <hip/hip_bf16.h>
#include <hip/hip_fp16.h>
#include <stdint.h>

#define BB 64
#define TT 512
#define II 256
#define HH 1024
#define G4 4096

typedef unsigned short u16;
typedef __attribute__((ext_vector_type(8))) _Float16 h8;
typedef __attribute__((ext_vector_type(4))) float f32x4;

__device__ __forceinline__ u16 f2h(float x){
  _Float16 h = (_Float16)x;
  return __builtin_bit_cast(u16, h);
}
__device__ __forceinline__ float sigm(float x){ return 1.0f/(1.0f + __expf(-x)); }
__device__ __forceinline__ float tanh_f(float x){ return 1.0f - 2.0f/(1.0f + __expf(2.0f*x)); }

// agent-scope (cross-XCD coherent) 16B load as two relaxed 8B atomics
__device__ __forceinline__ h8 aload16(const u16* p){
  union { unsigned long long v[2]; h8 h; } u;
  const unsigned long long* q = (const unsigned long long*)p;
  u.v[0] = __hip_atomic_load(q,     __ATOMIC_RELAXED, __HIP_MEMORY_SCOPE_AGENT);
  u.v[1] = __hip_atomic_load(q + 1, __ATOMIC_RELAXED, __HIP_MEMORY_SCOPE_AGENT);
  return u.h;
}

// ---------------- prep kernels ----------------
__global__ void bias_comb_kernel(const float* __restrict__ a, const float* __restrict__ b,
                                 float* __restrict__ o, int n){
  int i = blockIdx.x*blockDim.x + threadIdx.x;
  if (i < n) o[i] = a[i] + b[i];
}

// x: [B][T][I] fp32 -> xb: [(t*B+b)][I] fp16
__global__ void xconv_kernel(const float* __restrict__ x, u16* __restrict__ xb){
  int m = blockIdx.x;            // t*BB + b
  int t = m >> 6, b = m & 63;
  const float4* src = (const float4*)(x + ((size_t)b*TT + t)*II);
  float4 v = src[threadIdx.x];   // 64 threads * 4 = 256 = II
  ushort4 o; o.x=f2h(v.x); o.y=f2h(v.y); o.z=f2h(v.z); o.w=f2h(v.w);
  ((ushort4*)(xb + (size_t)m*II))[threadIdx.x] = o;
}

// Concat-K weight swizzle into MFMA B-frag order (fp32 -> fp16).
__global__ void wswz_kernel(const float* __restrict__ Wa, int Ka,
                            const float* __restrict__ Wb, int Kb,
                            u16* __restrict__ dst, int KS){
  int s8 = blockIdx.x*blockDim.x + threadIdx.x;
  int lane = s8 & 63;
  int g    = (s8 >> 6) & 3;
  int rest = s8 >> 8;
  int ks   = rest % KS;
  int jg   = rest / KS;
  if (jg >= 64) return;
  int id = lane & 15, quad = lane >> 4;
  int n = g*HH + jg*16 + id;
  int k = ks*32 + quad*8;
  const float* src = (k < Ka) ? (Wa + (size_t)n*Ka + k) : (Wb + (size_t)n*Kb + (k - Ka));
  float4 v0 = ((const float4*)src)[0];
  float4 v1 = ((const float4*)src)[1];
  ushort4 o0; o0.x=f2h(v0.x); o0.y=f2h(v0.y); o0.z=f2h(v0.z); o0.w=f2h(v0.w);
  ushort4 o1; o1.x=f2h(v1.x); o1.y=f2h(v1.y); o1.z=f2h(v1.z); o1.w=f2h(v1.w);
  u16* d = dst + (size_t)s8*8;
  ((ushort4*)d)[0] = o0;
  ((ushort4*)d)[1] = o1;
}

#define MF4(a, wp, A) \
  A[0] = __builtin_amdgcn_mfma_f32_16x16x32_f16((a), *(const h8*)((wp)       ), A[0], 0,0,0); \
  A[1] = __builtin_amdgcn_mfma_f32_16x16x32_f16((a), *(const h8*)((wp) +  512), A[1], 0,0,0); \
  A[2] = __builtin_amdgcn_mfma_f32_16x16x32_f16((a), *(const h8*)((wp) + 1024), A[2], 0,0,0); \
  A[3] = __builtin_amdgcn_mfma_f32_16x16x32_f16((a), *(const h8*)((wp) + 1536), A[3], 0,0,0);

// ---------------- fused 2-layer persistent LSTM, stamp-synchronized ----------------
// 128 blocks x 256 threads. blocks 0..63: layer0; 64..127: layer1.
// NO global barrier. h ring buffers with 8 slots. Producer protocol per epoch t:
//   store h[t] into slot (t+1)&7 -> __syncthreads (drains store acks at coherence
//   point) -> tid0 stores stamp = t+1 (relaxed agent).
// Consumer protocol: poll the 64 producer stamps (one lane each) until >= needed,
//   then __syncthreads, then load h (relaxed agent; L2 lines invalidated by the
//   remote stores, so post-stamp loads see fresh data).
// Layer decoupling: L0 free-runs ahead of L1. Anti-overwrite of y0 slots bounded
// by a LAZY credit scan of L1's stamps (every ~6 epochs, off critical path).
__launch_bounds__(256, 1)
__global__ void lstm_fused_kernel(const u16* __restrict__ xb,
                                  const u16* __restrict__ Wsw0,
                                  const u16* __restrict__ Wsw1,
                                  const float* __restrict__ bias0,
                                  const float* __restrict__ bias1,
                                  u16* __restrict__ h0buf,   // 8 slots [64][1024] fp16
                                  u16* __restrict__ h1buf,   // 8 slots
                                  float* __restrict__ hfin,  // [2][64][1024] fp32
                                  int* __restrict__ stamp0,  // 64 slots, stride 32 ints
                                  int* __restrict__ stamp1){ // 64 slots, stride 32 ints
  __shared__ float Gs[64*68];        // gate-rows(4g x 16j) x batches(64+pad)
  const int blk = blockIdx.x;
  const int layer = blk >> 6;
  const int jg = blk & 63;
  const int tid = threadIdx.x, wave = tid >> 6, lane = tid & 63;
  const int id = lane & 15, quad = lane >> 4;
  const int KS = layer ? 64 : 40;
  const u16* Wblk = (layer ? Wsw1 : Wsw0) + (size_t)jg * KS * 2048;
  const int ab = wave*16 + id;       // A-row (batch) this lane loads
  const int cb = tid >> 2, jq = tid & 3;  // cell phase: batch cb, j-quad jq
  const int j0 = jg * 16;
  const float* Bp = layer ? bias1 : bias0;
  float bs[4][4];
  #pragma unroll
  for (int g = 0; g < 4; ++g)
    #pragma unroll
    for (int jj = 0; jj < 4; ++jj)
      bs[g][jj] = Bp[g*HH + j0 + jq*4 + jj];
  float c4[4] = {0.f, 0.f, 0.f, 0.f};

  if (layer == 0){
    int credit = 0;   // cached lower bound on min(L1 stamps), wave0 lanes only
    for (int t = 0; t < TT; ++t){
      const u16* hA = h0buf + ((size_t)(t & 7) << 16);        // h0[t-1]
      u16* hout     = h0buf + ((size_t)((t + 1) & 7) << 16);  // h0[t]
      f32x4 accA[4] = {}, accB[4] = {};
      // ---- h-independent x-part: overlaps the stamp wait below ----
      const u16* xrow = xb + ((size_t)(t*64 + ab) << 8);
      #pragma unroll
      for (int ks = 0; ks < 8; ++ks){
        h8 a = *(const h8*)(xrow + ks*32 + quad*8);
        MF4(a, Wblk + (size_t)ks*2048 + lane*8, accA);
      }
      // ---- wait: all L0 peers have published h0[t-1] ----
      if (tid < 64){
        while (__hip_atomic_load(stamp0 + tid*32, __ATOMIC_RELAXED, __HIP_MEMORY_SCOPE_AGENT) < t)
          __builtin_amdgcn_s_sleep(2);
        // lazy credit: before overwriting slot (t+1)&7 (= y0[t-8]), all L1 >= t-7.
        while (credit < t - 7){
          int s = __hip_atomic_load(stamp1 + tid*32, __ATOMIC_RELAXED, __HIP_MEMORY_SCOPE_AGENT);
          #pragma unroll
          for (int off = 32; off; off >>= 1){
            int s2 = __shfl_xor(s, off);
            s = s < s2 ? s : s2;
          }
          credit = s;
          if (credit < t - 7) __builtin_amdgcn_s_sleep(8);
        }
      }
      __syncthreads();
      // ---- h-part ----
      const u16* hrow = hA + ((size_t)ab << 10) + quad*8;
      #pragma unroll 8
      for (int ks = 0; ks < 16; ++ks){
        h8 a0 = aload16(hrow + ks*32);
        h8 a1 = aload16(hrow + (ks + 16)*32);
        MF4(a0, Wblk + (size_t)(8 + ks)*2048 + lane*8, accA);
        MF4(a1, Wblk + (size_t)(24 + ks)*2048 + lane*8, accB);
      }
      // exchange: D lane(id,quad),reg r -> batch = wave*16 + quad*4 + r, gate-row = g*16 + id
      #pragma unroll
      for (int g = 0; g < 4; ++g){
        f32x4 s = accA[g] + accB[g];
        *(f32x4*)&Gs[(size_t)(g*16 + id)*68 + wave*16 + quad*4] = s;
      }
      __syncthreads();
      ushort4 hb; float4 hf;
      #pragma unroll
      for (int jj = 0; jj < 4; ++jj){
        int jl = jq*4 + jj;
        float pi = Gs[(     jl)*68 + cb] + bs[0][jj];
        float pf = Gs[(16 + jl)*68 + cb] + bs[1][jj];
        float pg = Gs[(32 + jl)*68 + cb] + bs[2][jj];
        float po = Gs[(48 + jl)*68 + cb] + bs[3][jj];
        float iv = sigm(pi), fv = sigm(pf), gv = tanh_f(pg), ov = sigm(po);
        float c = fv*c4[jj] + iv*gv;
        c4[jj] = c;
        float h = ov * tanh_f(c);
        (&hf.x)[jj] = h;
        ((u16*)&hb)[jj] = f2h(h);
      }
      union { ushort4 s; unsigned long long v; } pk; pk.s = hb;
      __hip_atomic_store((unsigned long long*)&hout[(size_t)cb*HH + j0 + jq*4],
                         pk.v, __ATOMIC_RELAXED, __HIP_MEMORY_SCOPE_AGENT);
      if (t == TT - 1)
        *(float4*)&hfin[(size_t)cb*HH + j0 + jq*4] = hf;
      __syncthreads();   // drains vmcnt: h-stores ack'd at coherence point
      if (tid == 0)
        __hip_atomic_store(stamp0 + jg*32, t + 1, __ATOMIC_RELAXED, __HIP_MEMORY_SCOPE_AGENT);
    }
  } else {
    for (int t = 0; t < TT; ++t){
      const u16* y0 = h0buf + ((size_t)((t + 1) & 7) << 16);  // y0[t] = h0[t]
      const u16* hA = h1buf + ((size_t)(t & 7) << 16);        // h1[t-1]
      u16* hout     = h1buf + ((size_t)((t + 1) & 7) << 16);  // h1[t]
      // ---- wait: L0 published h0[t] (stamp >= t+1), L1 peers published h1[t-1] ----
      if (tid < 64){
        while (__hip_atomic_load(stamp0 + tid*32, __ATOMIC_RELAXED, __HIP_MEMORY_SCOPE_AGENT) < t + 1)
          __builtin_amdgcn_s_sleep(2);
      } else if (tid < 128){
        while (__hip_atomic_load(stamp1 + (tid & 63)*32, __ATOMIC_RELAXED, __HIP_MEMORY_SCOPE_AGENT) < t)
          __builtin_amdgcn_s_sleep(2);
      }
      __syncthreads();
      f32x4 accA[4] = {}, accB[4] = {};
      const u16* y0row = y0 + ((size_t)ab << 10) + quad*8;
      const u16* h1row = hA + ((size_t)ab << 10) + quad*8;
      #pragma unroll 8
      for (int ks = 0; ks < 32; ++ks){
        h8 a0 = aload16(y0row + ks*32);
        h8 a1 = aload16(h1row + ks*32);
        MF4(a0, Wblk + (size_t)ks*2048 + lane*8, accA);
        MF4(a1, Wblk + (size_t)(ks + 32)*2048 + lane*8, accB);
      }
      #pragma unroll
      for (int g = 0; g < 4; ++g){
        f32x4 s = accA[g] + accB[g];
        *(f32x4*)&Gs[(size_t)(g*16 + id)*68 + wave*16 + quad*4] = s;
      }
      __syncthreads();
      ushort4 hb; float4 hf;
      #pragma unroll
      for (int jj = 0; jj < 4; ++jj){
        int jl = jq*4 + jj;
        float pi = Gs[(     jl)*68 + cb] + bs[0][jj];
        float pf = Gs[(16 + jl)*68 + cb] + bs[1][jj];
        float pg = Gs[(32 + jl)*68 + cb] + bs[2][jj];
        float po = Gs[(48 + jl)*68 + cb] + bs[3][jj];
        float iv = sigm(pi), fv = sigm(pf), gv = tanh_f(pg), ov = sigm(po);
        float c = fv*c4[jj] + iv*gv;
        c4[jj] = c;
        float h = ov * tanh_f(c);
        (&hf.x)[jj] = h;
        ((u16*)&hb)[jj] = f2h(h);
      }
      union { ushort4 s; unsigned long long v; } pk; pk.s = hb;
      __hip_atomic_store((unsigned long long*)&hout[(size_t)cb*HH + j0 + jq*4],
                         pk.v, __ATOMIC_RELAXED, __HIP_MEMORY_SCOPE_AGENT);
      if (t == TT - 1)
        *(float4*)&hfin[(size_t)(BB*HH) + (size_t)cb*HH + j0 + jq*4] = hf;
      __syncthreads();   // drains vmcnt: h-stores ack'd at coherence point
      if (tid == 0)
        __hip_atomic_store(stamp1 + jg*32, t + 1, __ATOMIC_RELAXED, __HIP_MEMORY_SCOPE_AGENT);
    }
  }
}

// ---------------- FC head ----------------
__global__ void fc_kernel(const float* __restrict__ hfin, const float* __restrict__ fcw,
                          const float* __restrict__ fcb, float* __restrict__ out){
  int row = blockIdx.x;          // 0..127  (0..63 layer0 hT, 64..127 layer1 hT)
  int lane = threadIdx.x;        // 64
  const float* h = hfin + (size_t)row*HH;
  float a0 = 0.f, a1 = 0.f;
  for (int j = lane; j < HH; j += 64){
    float v = h[j]; v = v > 0.f ? v : 0.f;
    a0 += v * fcw[j];
    a1 += v * fcw[HH + j];
  }
  for (int off = 32; off; off >>= 1){ a0 += __shfl_down(a0, off); a1 += __shfl_down(a1, off); }
  if (lane == 0){
    out[row*2 + 0] = 1.f/(1.f + __expf(-(a0 + fcb[0])));
    out[row*2 + 1] = 1.f/(1.f + __expf(-(a1 + fcb[1])));
  }
}

// ---------------- launch ----------------
extern "C" void kernel_launch(void* const* d_in, const int* in_sizes, int n_in,
                              void* d_out, int out_size, void* d_ws, size_t ws_size,
                              hipStream_t stream){
  (void)in_sizes; (void)n_in; (void)out_size; (void)ws_size;
  const float* x    = (const float*)d_in[0];
  const float* Wih0 = (const float*)d_in[1];
  const float* Whh0 = (const float*)d_in[2];
  const float* bih0 = (const float*)d_in[3];
  const float* bhh0 = (const float*)d_in[4];
  const float* Wih1 = (const float*)d_in[5];
  const float* Whh1 = (const float*)d_in[6];
  const float* bih1 = (const float*)d_in[7];
  const float* bhh1 = (const float*)d_in[8];
  const float* fcw  = (const float*)d_in[9];
  const float* fcb  = (const float*)d_in[10];

  char* w = (char*)d_ws;
  size_t off = 0;
  auto take = [&](size_t bytes)->char*{
    char* p = w + off; off += (bytes + 255) & ~(size_t)255; return p;
  };
  u16*   xb    = (u16*)  take((size_t)TT*BB*II*2);       // 16 MB
  u16*   wsw0  = (u16*)  take((size_t)G4*1280*2);        // 10 MB  (K=256+1024)
  u16*   wsw1  = (u16*)  take((size_t)G4*2048*2);        // 16 MB  (K=1024+1024)
  float* bias0 = (float*)take(G4*4);
  float* bias1 = (float*)take(G4*4);
  u16*   h0buf = (u16*)  take(8*(size_t)BB*HH*2);        // 1 MB ring (8 slots)
  u16*   h1buf = (u16*)  take(8*(size_t)BB*HH*2);
  float* hfin  = (float*)take(2*(size_t)BB*HH*4);        // 512 KB
  int*   stamp0= (int*)  take(64*128);                   // 64 slots x 128B
  int*   stamp1= (int*)  take(64*128);

  hipMemsetAsync(h0buf, 0, 8*(size_t)BB*HH*2, stream);
  hipMemsetAsync(h1buf, 0, 8*(size_t)BB*HH*2, stream);
  hipMemsetAsync(stamp0, 0, 64*128, stream);
  hipMemsetAsync(stamp1, 0, 64*128, stream);

  bias_comb_kernel<<<16, 256, 0, stream>>>(bih0, bhh0, bias0, G4);
  bias_comb_kernel<<<16, 256, 0, stream>>>(bih1, bhh1, bias1, G4);
  xconv_kernel<<<TT*BB, 64, 0, stream>>>(x, xb);
  // L0: K=1280 (KS=40): 64*40*4*64/256 = 2560 blocks; L1: K=2048 (KS=64): 4096 blocks
  wswz_kernel<<<2560, 256, 0, stream>>>(Wih0, II, Whh0, HH, wsw0, 40);
  wswz_kernel<<<4096, 256, 0, stream>>>(Wih1, HH, Whh1, HH, wsw1, 64);

  lstm_fused_kernel<<<128, 256, 0, stream>>>(xb, wsw0, wsw1, bias0, bias1,
                                             h0buf, h1buf, hfin, stamp0, stamp1);
  fc_kernel<<<2*BB, 64, 0, stream>>>(hfin, fcw, fcb, (float*)d_out);
}

// Round 3
// 11451.398 us; speedup vs baseline: 1.4762x; 1.3298x over previous
//
#include <hip/hip_runtime.h>
#include <hip/hip_bf16.h>
#include <hip/hip_fp16.h>
#include <stdint.h>

#define BB 64
#define TT 512
#define II 256
#define HH 1024
#define G4 4096

typedef unsigned short u16;
typedef __attribute__((ext_vector_type(8))) _Float16 h8;
typedef __attribute__((ext_vector_type(4))) float f32x4;

__device__ __forceinline__ u16 f2h(float x){
  _Float16 h = (_Float16)x;
  return __builtin_bit_cast(u16, h);
}
__device__ __forceinline__ float sigm(float x){ return 1.0f/(1.0f + __expf(-x)); }
__device__ __forceinline__ float tanh_f(float x){ return 1.0f - 2.0f/(1.0f + __expf(2.0f*x)); }

// agent-scope (cross-XCD coherent) 16B load as two relaxed 8B atomics
__device__ __forceinline__ h8 aload16(const u16* p){
  union { unsigned long long v[2]; h8 h; } u;
  const unsigned long long* q = (const unsigned long long*)p;
  u.v[0] = __hip_atomic_load(q,     __ATOMIC_RELAXED, __HIP_MEMORY_SCOPE_AGENT);
  u.v[1] = __hip_atomic_load(q + 1, __ATOMIC_RELAXED, __HIP_MEMORY_SCOPE_AGENT);
  return u.h;
}

// ---------------- prep kernels ----------------
__global__ void bias_comb_kernel(const float* __restrict__ a, const float* __restrict__ b,
                                 float* __restrict__ o, int n){
  int i = blockIdx.x*blockDim.x + threadIdx.x;
  if (i < n) o[i] = a[i] + b[i];
}

// x: [B][T][I] fp32 -> xb: [(t*B+b)][I] fp16
__global__ void xconv_kernel(const float* __restrict__ x, u16* __restrict__ xb){
  int m = blockIdx.x;            // t*BB + b
  int t = m >> 6, b = m & 63;
  const float4* src = (const float4*)(x + ((size_t)b*TT + t)*II);
  float4 v = src[threadIdx.x];   // 64 threads * 4 = 256 = II
  ushort4 o; o.x=f2h(v.x); o.y=f2h(v.y); o.z=f2h(v.z); o.w=f2h(v.w);
  ((ushort4*)(xb + (size_t)m*II))[threadIdx.x] = o;
}

// Concat-K weight swizzle into MFMA B-frag order (fp32 -> fp16).
// 8-j blocks: frag f in {0,1}; within frag, id in [0,16):
//   gate g = f*2 + (id>>3), j = jg8*8 + (id&7), n = g*HH + j
//   k = ks*32 + quad*8 + elem
// dst s8 = ((jg8*KS + ks)*2 + f)*64 + lane, 8 u16 each.
__global__ void wswz_kernel(const float* __restrict__ Wa, int Ka,
                            const float* __restrict__ Wb, int Kb,
                            u16* __restrict__ dst, int KS){
  int s8 = blockIdx.x*blockDim.x + threadIdx.x;
  int lane = s8 & 63;
  int f    = (s8 >> 6) & 1;
  int rest = s8 >> 7;
  int ks   = rest % KS;
  int jg8  = rest / KS;
  if (jg8 >= 128) return;
  int id = lane & 15, quad = lane >> 4;
  int g = f*2 + (id >> 3);
  int n = g*HH + jg8*8 + (id & 7);
  int k = ks*32 + quad*8;
  const float* src = (k < Ka) ? (Wa + (size_t)n*Ka + k) : (Wb + (size_t)n*Kb + (k - Ka));
  float4 v0 = ((const float4*)src)[0];
  float4 v1 = ((const float4*)src)[1];
  ushort4 o0; o0.x=f2h(v0.x); o0.y=f2h(v0.y); o0.z=f2h(v0.z); o0.w=f2h(v0.w);
  ushort4 o1; o1.x=f2h(v1.x); o1.y=f2h(v1.y); o1.z=f2h(v1.z); o1.w=f2h(v1.w);
  u16* d = dst + (size_t)s8*8;
  ((ushort4*)d)[0] = o0;
  ((ushort4*)d)[1] = o1;
}

// ---------------- fused 2-layer persistent LSTM, stamp-synchronized ----------------
// 256 blocks x 256 threads. blocks 0..127: layer0 (jg8 = blk, 8 h-cols each);
// blocks 128..255: layer1. K-SPLIT ACROSS WAVES: wave w owns K-quarter
// [w*KS/4, (w+1)*KS/4) for ALL 64 batches (4 M-tiles), so the 4 waves read
// DISJOINT weight fragments (no intra-block duplication through L1).
// Partial sums reduced via LDS Gs[wave] segments, summed in the cell phase.
// Sync: per-block stamps (agent scope), h ring buffers (8 slots), L0 free-runs
// ahead of L1 bounded by a lazy credit scan. No global barrier.
__launch_bounds__(256, 1)
__global__ void lstm_fused_kernel(const u16* __restrict__ xb,
                                  const u16* __restrict__ Wsw0,
                                  const u16* __restrict__ Wsw1,
                                  const float* __restrict__ bias0,
                                  const float* __restrict__ bias1,
                                  u16* __restrict__ h0buf,   // 8 slots [64][1024] fp16
                                  u16* __restrict__ h1buf,   // 8 slots
                                  float* __restrict__ hfin,  // [2][64][1024] fp32
                                  int* __restrict__ stamp0,  // 128 slots, stride 32 ints
                                  int* __restrict__ stamp1){ // 128 slots, stride 32 ints
  __shared__ float Gs[4][32][68];    // [wave][gate-row 2f x 16id][batch 64+pad]
  const int blk = blockIdx.x;
  const int layer = blk >> 7;
  const int jg = blk & 127;
  const int tid = threadIdx.x, wave = tid >> 6, lane = tid & 63;
  const int id = lane & 15, quad = lane >> 4;
  const int KS = layer ? 64 : 40;
  const int KSW = layer ? 16 : 10;
  const u16* Wblk = (layer ? Wsw1 : Wsw0) + (size_t)jg * KS * 1024;
  const int cb = tid >> 2, jq = tid & 3;  // cell phase: batch cb, j-pair jq
  const int j0 = jg * 8;
  const float* Bp = layer ? bias1 : bias0;
  float bs[4][2];
  #pragma unroll
  for (int g = 0; g < 4; ++g)
    #pragma unroll
    for (int jj = 0; jj < 2; ++jj)
      bs[g][jj] = Bp[g*HH + j0 + jq*2 + jj];
  float c2[2] = {0.f, 0.f};
  const int wb = wave * KSW;

  if (layer == 0){
    int credit = 0;   // cached lower bound on min(L1 stamps), wave0 lanes only
    for (int t = 0; t < TT; ++t){
      const u16* hA = h0buf + ((size_t)(t & 7) << 16);        // h0[t-1]
      u16* hout     = h0buf + ((size_t)((t + 1) & 7) << 16);  // h0[t]
      // ---- wait: all L0 peers have published h0[t-1]; lazy anti-overwrite credit ----
      if (tid < 128){
        while (__hip_atomic_load(stamp0 + tid*32, __ATOMIC_RELAXED, __HIP_MEMORY_SCOPE_AGENT) < t)
          __builtin_amdgcn_s_sleep(2);
      }
      if (tid < 64){
        while (credit < t - 7){
          int sa = __hip_atomic_load(stamp1 + tid*32,      __ATOMIC_RELAXED, __HIP_MEMORY_SCOPE_AGENT);
          int sb = __hip_atomic_load(stamp1 + (64+tid)*32, __ATOMIC_RELAXED, __HIP_MEMORY_SCOPE_AGENT);
          int s = sa < sb ? sa : sb;
          #pragma unroll
          for (int off = 32; off; off >>= 1){
            int s2 = __shfl_xor(s, off);
            s = s < s2 ? s : s2;
          }
          credit = s;
          if (credit < t - 7) __builtin_amdgcn_s_sleep(8);
        }
      }
      __syncthreads();
      // ---- GEMM: wave w covers k in [wb*32, (wb+10)*32) of 1280 (256 x | 1024 h) ----
      f32x4 a0[4] = {}, a1[4] = {};
      #pragma unroll 5
      for (int l = 0; l < 10; ++l){
        const u16* wl = Wblk + (size_t)(wb + l)*1024 + lane*8;
        h8 b0 = *(const h8*)(wl);
        h8 b1 = *(const h8*)(wl + 512);
        int kg = (wb + l)*32 + quad*8;
        #pragma unroll
        for (int mt = 0; mt < 4; ++mt){
          int abm = mt*16 + id;
          h8 a;
          if (kg < 256) a = *(const h8*)(xb + (((size_t)t*64 + abm) << 8) + kg);
          else          a = aload16(hA + ((size_t)abm << 10) + (kg - 256));
          a0[mt] = __builtin_amdgcn_mfma_f32_16x16x32_f16(a, b0, a0[mt], 0,0,0);
          a1[mt] = __builtin_amdgcn_mfma_f32_16x16x32_f16(a, b1, a1[mt], 0,0,0);
        }
      }
      // ---- exchange: D lane(id,quad) reg r -> batch mt*16+quad*4+r, row f*16+id ----
      #pragma unroll
      for (int mt = 0; mt < 4; ++mt){
        *(f32x4*)&Gs[wave][id][mt*16 + quad*4]      = a0[mt];
        *(f32x4*)&Gs[wave][16 + id][mt*16 + quad*4] = a1[mt];
      }
      __syncthreads();
      // ---- cell phase: 2 cells (batch cb, j = j0 + jq*2 + jj) ----
      ushort2 hb; float2 hf;
      #pragma unroll
      for (int jj = 0; jj < 2; ++jj){
        int jl = jq*2 + jj;
        float p[4];
        #pragma unroll
        for (int g = 0; g < 4; ++g){
          int e = (g >> 1)*16 + (g & 1)*8 + jl;
          p[g] = Gs[0][e][cb] + Gs[1][e][cb] + Gs[2][e][cb] + Gs[3][e][cb] + bs[g][jj];
        }
        float iv = sigm(p[0]), fv = sigm(p[1]), gv = tanh_f(p[2]), ov = sigm(p[3]);
        float c = fv*c2[jj] + iv*gv;
        c2[jj] = c;
        float h = ov * tanh_f(c);
        (&hf.x)[jj] = h;
        ((u16*)&hb)[jj] = f2h(h);
      }
      union { ushort2 s; unsigned int v; } pk; pk.s = hb;
      __hip_atomic_store((unsigned int*)&hout[(size_t)cb*HH + j0 + jq*2],
                         pk.v, __ATOMIC_RELAXED, __HIP_MEMORY_SCOPE_AGENT);
      if (t == TT - 1)
        *(float2*)&hfin[(size_t)cb*HH + j0 + jq*2] = hf;
      __syncthreads();   // drains vmcnt: h-stores ack'd at coherence point
      if (tid == 0)
        __hip_atomic_store(stamp0 + jg*32, t + 1, __ATOMIC_RELAXED, __HIP_MEMORY_SCOPE_AGENT);
    }
  } else {
    for (int t = 0; t < TT; ++t){
      const u16* y0 = h0buf + ((size_t)((t + 1) & 7) << 16);  // y0[t] = h0[t]
      const u16* hA = h1buf + ((size_t)(t & 7) << 16);        // h1[t-1]
      u16* hout     = h1buf + ((size_t)((t + 1) & 7) << 16);  // h1[t]
      // ---- wait: L0 published h0[t] (stamp >= t+1); L1 peers published h1[t-1] ----
      if (tid < 128){
        while (__hip_atomic_load(stamp0 + tid*32, __ATOMIC_RELAXED, __HIP_MEMORY_SCOPE_AGENT) < t + 1)
          __builtin_amdgcn_s_sleep(2);
      } else {
        while (__hip_atomic_load(stamp1 + (tid & 127)*32, __ATOMIC_RELAXED, __HIP_MEMORY_SCOPE_AGENT) < t)
          __builtin_amdgcn_s_sleep(2);
      }
      __syncthreads();
      // ---- GEMM: wave w covers k in [wb*32, (wb+16)*32) of 2048 (1024 y0 | 1024 h1) ----
      f32x4 a0[4] = {}, a1[4] = {};
      #pragma unroll 4
      for (int l = 0; l < 16; ++l){
        const u16* wl = Wblk + (size_t)(wb + l)*1024 + lane*8;
        h8 b0 = *(const h8*)(wl);
        h8 b1 = *(const h8*)(wl + 512);
        int kg = (wb + l)*32 + quad*8;
        #pragma unroll
        for (int mt = 0; mt < 4; ++mt){
          int abm = mt*16 + id;
          h8 a;
          if (kg < 1024) a = aload16(y0 + ((size_t)abm << 10) + kg);
          else           a = aload16(hA + ((size_t)abm << 10) + (kg - 1024));
          a0[mt] = __builtin_amdgcn_mfma_f32_16x16x32_f16(a, b0, a0[mt], 0,0,0);
          a1[mt] = __builtin_amdgcn_mfma_f32_16x16x32_f16(a, b1, a1[mt], 0,0,0);
        }
      }
      #pragma unroll
      for (int mt = 0; mt < 4; ++mt){
        *(f32x4*)&Gs[wave][id][mt*16 + quad*4]      = a0[mt];
        *(f32x4*)&Gs[wave][16 + id][mt*16 + quad*4] = a1[mt];
      }
      __syncthreads();
      ushort2 hb; float2 hf;
      #pragma unroll
      for (int jj = 0; jj < 2; ++jj){
        int jl = jq*2 + jj;
        float p[4];
        #pragma unroll
        for (int g = 0; g < 4; ++g){
          int e = (g >> 1)*16 + (g & 1)*8 + jl;
          p[g] = Gs[0][e][cb] + Gs[1][e][cb] + Gs[2][e][cb] + Gs[3][e][cb] + bs[g][jj];
        }
        float iv = sigm(p[0]), fv = sigm(p[1]), gv = tanh_f(p[2]), ov = sigm(p[3]);
        float c = fv*c2[jj] + iv*gv;
        c2[jj] = c;
        float h = ov * tanh_f(c);
        (&hf.x)[jj] = h;
        ((u16*)&hb)[jj] = f2h(h);
      }
      union { ushort2 s; unsigned int v; } pk; pk.s = hb;
      __hip_atomic_store((unsigned int*)&hout[(size_t)cb*HH + j0 + jq*2],
                         pk.v, __ATOMIC_RELAXED, __HIP_MEMORY_SCOPE_AGENT);
      if (t == TT - 1)
        *(float2*)&hfin[(size_t)(BB*HH) + (size_t)cb*HH + j0 + jq*2] = hf;
      __syncthreads();   // drains vmcnt: h-stores ack'd at coherence point
      if (tid == 0)
        __hip_atomic_store(stamp1 + jg*32, t + 1, __ATOMIC_RELAXED, __HIP_MEMORY_SCOPE_AGENT);
    }
  }
}

// ---------------- FC head ----------------
__global__ void fc_kernel(const float* __restrict__ hfin, const float* __restrict__ fcw,
                          const float* __restrict__ fcb, float* __restrict__ out){
  int row = blockIdx.x;          // 0..127  (0..63 layer0 hT, 64..127 layer1 hT)
  int lane = threadIdx.x;        // 64
  const float* h = hfin + (size_t)row*HH;
  float a0 = 0.f, a1 = 0.f;
  for (int j = lane; j < HH; j += 64){
    float v = h[j]; v = v > 0.f ? v : 0.f;
    a0 += v * fcw[j];
    a1 += v * fcw[HH + j];
  }
  for (int off = 32; off; off >>= 1){ a0 += __shfl_down(a0, off); a1 += __shfl_down(a1, off); }
  if (lane == 0){
    out[row*2 + 0] = 1.f/(1.f + __expf(-(a0 + fcb[0])));
    out[row*2 + 1] = 1.f/(1.f + __expf(-(a1 + fcb[1])));
  }
}

// ---------------- launch ----------------
extern "C" void kernel_launch(void* const* d_in, const int* in_sizes, int n_in,
                              void* d_out, int out_size, void* d_ws, size_t ws_size,
                              hipStream_t stream){
  (void)in_sizes; (void)n_in; (void)out_size; (void)ws_size;
  const float* x    = (const float*)d_in[0];
  const float* Wih0 = (const float*)d_in[1];
  const float* Whh0 = (const float*)d_in[2];
  const float* bih0 = (const float*)d_in[3];
  const float* bhh0 = (const float*)d_in[4];
  const float* Wih1 = (const float*)d_in[5];
  const float* Whh1 = (const float*)d_in[6];
  const float* bih1 = (const float*)d_in[7];
  const float* bhh1 = (const float*)d_in[8];
  const float* fcw  = (const float*)d_in[9];
  const float* fcb  = (const float*)d_in[10];

  char* w = (char*)d_ws;
  size_t off = 0;
  auto take = [&](size_t bytes)->char*{
    char* p = w + off; off += (bytes + 255) & ~(size_t)255; return p;
  };
  u16*   xb    = (u16*)  take((size_t)TT*BB*II*2);       // 16 MB
  u16*   wsw0  = (u16*)  take((size_t)G4*1280*2);        // 10 MB  (K=256+1024)
  u16*   wsw1  = (u16*)  take((size_t)G4*2048*2);        // 16 MB  (K=1024+1024)
  float* bias0 = (float*)take(G4*4);
  float* bias1 = (float*)take(G4*4);
  u16*   h0buf = (u16*)  take(8*(size_t)BB*HH*2);        // 1 MB ring (8 slots)
  u16*   h1buf = (u16*)  take(8*(size_t)BB*HH*2);
  float* hfin  = (float*)take(2*(size_t)BB*HH*4);        // 512 KB
  int*   stamp0= (int*)  take(128*128);                  // 128 slots x 128B
  int*   stamp1= (int*)  take(128*128);

  hipMemsetAsync(h0buf, 0, 8*(size_t)BB*HH*2, stream);
  hipMemsetAsync(h1buf, 0, 8*(size_t)BB*HH*2, stream);
  hipMemsetAsync(stamp0, 0, 128*128, stream);
  hipMemsetAsync(stamp1, 0, 128*128, stream);

  bias_comb_kernel<<<16, 256, 0, stream>>>(bih0, bhh0, bias0, G4);
  bias_comb_kernel<<<16, 256, 0, stream>>>(bih1, bhh1, bias1, G4);
  xconv_kernel<<<TT*BB, 64, 0, stream>>>(x, xb);
  // L0: 128*40*2*64/256 = 2560 blocks; L1: 128*64*2*64/256 = 4096 blocks
  wswz_kernel<<<2560, 256, 0, stream>>>(Wih0, II, Whh0, HH, wsw0, 40);
  wswz_kernel<<<4096, 256, 0, stream>>>(Wih1, HH, Whh1, HH, wsw1, 64);

  lstm_fused_kernel<<<256, 256, 0, stream>>>(xb, wsw0, wsw1, bias0, bias1,
                                             h0buf, h1buf, hfin, stamp0, stamp1);
  fc_kernel<<<2*BB, 64, 0, stream>>>(hfin, fcw, fcb, (float*)d_out);
}

// Round 5
// 8492.672 us; speedup vs baseline: 1.9905x; 1.3484x over previous
//
#include <hip/hip_runtime.h>
#include <hip/hip_bf16.h>
#include <hip/hip_fp16.h>
#include <stdint.h>

#define BB 64
#define TT 512
#define II 256
#define HH 1024
#define G4 4096

typedef unsigned short u16;
typedef __attribute__((ext_vector_type(8))) _Float16 h8;
typedef __attribute__((ext_vector_type(4))) float f32x4;

__device__ __forceinline__ u16 f2h(float x){
  _Float16 h = (_Float16)x;
  return __builtin_bit_cast(u16, h);
}
__device__ __forceinline__ float sigm(float x){ return 1.0f/(1.0f + __expf(-x)); }
__device__ __forceinline__ float tanh_f(float x){ return 1.0f - 2.0f/(1.0f + __expf(2.0f*x)); }

// agent-scope (cross-XCD coherent) 16B load as two relaxed 8B atomics
__device__ __forceinline__ h8 aload16(const u16* p){
  union { unsigned long long v[2]; h8 h; } u;
  const unsigned long long* q = (const unsigned long long*)p;
  u.v[0] = __hip_atomic_load(q,     __ATOMIC_RELAXED, __HIP_MEMORY_SCOPE_AGENT);
  u.v[1] = __hip_atomic_load(q + 1, __ATOMIC_RELAXED, __HIP_MEMORY_SCOPE_AGENT);
  return u.h;
}

// ---------------- prep kernels ----------------
__global__ void bias_comb_kernel(const float* __restrict__ a, const float* __restrict__ b,
                                 float* __restrict__ o, int n){
  int i = blockIdx.x*blockDim.x + threadIdx.x;
  if (i < n) o[i] = a[i] + b[i];
}

// x: [B][T][I] fp32 -> xb: [(t*B+b)][I] fp16
__global__ void xconv_kernel(const float* __restrict__ x, u16* __restrict__ xb){
  int m = blockIdx.x;            // t*BB + b
  int t = m >> 6, b = m & 63;
  const float4* src = (const float4*)(x + ((size_t)b*TT + t)*II);
  float4 v = src[threadIdx.x];   // 64 threads * 4 = 256 = II
  ushort4 o; o.x=f2h(v.x); o.y=f2h(v.y); o.z=f2h(v.z); o.w=f2h(v.w);
  ((ushort4*)(xb + (size_t)m*II))[threadIdx.x] = o;
}

// Concat-K weight swizzle into MFMA B-frag order (fp32 -> fp16).
// 8-j blocks: frag f in {0,1}; within frag, id in [0,16):
//   gate g = f*2 + (id>>3), j = jg8*8 + (id&7), n = g*HH + j
//   k = ks*32 + quad*8 + elem
// dst s8 = ((jg8*KS + ks)*2 + f)*64 + lane, 8 u16 each.
__global__ void wswz_kernel(const float* __restrict__ Wa, int Ka,
                            const float* __restrict__ Wb, int Kb,
                            u16* __restrict__ dst, int KS){
  int s8 = blockIdx.x*blockDim.x + threadIdx.x;
  int lane = s8 & 63;
  int f    = (s8 >> 6) & 1;
  int rest = s8 >> 7;
  int ks   = rest % KS;
  int jg8  = rest / KS;
  if (jg8 >= 128) return;
  int id = lane & 15, quad = lane >> 4;
  int g = f*2 + (id >> 3);
  int n = g*HH + jg8*8 + (id & 7);
  int k = ks*32 + quad*8;
  const float* src = (k < Ka) ? (Wa + (size_t)n*Ka + k) : (Wb + (size_t)n*Kb + (k - Ka));
  float4 v0 = ((const float4*)src)[0];
  float4 v1 = ((const float4*)src)[1];
  ushort4 o0; o0.x=f2h(v0.x); o0.y=f2h(v0.y); o0.z=f2h(v0.z); o0.w=f2h(v0.w);
  ushort4 o1; o1.x=f2h(v1.x); o1.y=f2h(v1.y); o1.z=f2h(v1.z); o1.w=f2h(v1.w);
  u16* d = dst + (size_t)s8*8;
  ((ushort4*)d)[0] = o0;
  ((ushort4*)d)[1] = o1;
}

// ---------------- fused 2-layer persistent LSTM, weights-in-registers ----------------
// (Resubmission of round-4 kernel: prior bench died to container infra failure,
// no data collected. Protocol identical to the round-3 kernel that passed.)
// 256 blocks x 256 threads. blocks 0..127: layer0 (8 h-cols each); 128..255: layer1.
// K-split across waves; each wave PRELOADS its disjoint weight fragment into
// VGPRs once (L1: 128 VGPR, L0: 80 VGPR) -> ZERO weight traffic in the t-loop.
// Per-epoch loads are only the h exchange (agent-scope atomics) + x (L0).
// Sync: per-block stamps (agent scope), h ring buffers (8 slots), L0 free-runs
// ahead of L1 bounded by a lazy credit scan. No global barrier.
__launch_bounds__(256, 1)
__global__ void lstm_fused_kernel(const u16* __restrict__ xb,
                                  const u16* __restrict__ Wsw0,
                                  const u16* __restrict__ Wsw1,
                                  const float* __restrict__ bias0,
                                  const float* __restrict__ bias1,
                                  u16* __restrict__ h0buf,   // 8 slots [64][1024] fp16
                                  u16* __restrict__ h1buf,   // 8 slots
                                  float* __restrict__ hfin,  // [2][64][1024] fp32
                                  int* __restrict__ stamp0,  // 128 slots, stride 32 ints
                                  int* __restrict__ stamp1){ // 128 slots, stride 32 ints
  __shared__ float Gs[4][32][68];    // [wave][gate-row 2f x 16id][batch 64+pad]
  const int blk = blockIdx.x;
  const int layer = blk >> 7;
  const int jg = blk & 127;
  const int tid = threadIdx.x, wave = tid >> 6, lane = tid & 63;
  const int id = lane & 15, quad = lane >> 4;
  const int KS = layer ? 64 : 40;
  const int KSW = layer ? 16 : 10;
  const u16* Wblk = (layer ? Wsw1 : Wsw0) + (size_t)jg * KS * 1024;
  const int cb = tid >> 2, jq = tid & 3;  // cell phase: batch cb, j-pair jq
  const int j0 = jg * 8;
  const float* Bp = layer ? bias1 : bias0;
  float bs[4][2];
  #pragma unroll
  for (int g = 0; g < 4; ++g)
    #pragma unroll
    for (int jj = 0; jj < 2; ++jj)
      bs[g][jj] = Bp[g*HH + j0 + jq*2 + jj];
  float c2[2] = {0.f, 0.f};
  const int wb = wave * KSW;

  if (layer == 0){
    // ---- preload weight fragment: 10 steps x 2 frags = 80 VGPR ----
    h8 w0[10], w1[10];
    #pragma unroll
    for (int l = 0; l < 10; ++l){
      const u16* wl = Wblk + (size_t)(wb + l)*1024 + lane*8;
      w0[l] = *(const h8*)(wl);
      w1[l] = *(const h8*)(wl + 512);
    }
    // wave w covers k [w*320, w*320+320): wave0 = 256 x-cols + 64 h; waves1-3 all h
    const int hko = wb*32 - 256;               // h-offset of l=0 (may be <0 for wave0)
    const int lmin = (wave == 0) ? 8 : 0;      // first l that reads h
    int credit = 0;
    for (int t = 0; t < TT; ++t){
      const u16* hA = h0buf + ((size_t)(t & 7) << 16);        // h0[t-1]
      u16* hout     = h0buf + ((size_t)((t + 1) & 7) << 16);  // h0[t]
      f32x4 a0[4] = {}, a1[4] = {};
      // ---- x-part (wave0 only): h-independent, overlaps the stamp wait ----
      if (wave == 0){
        #pragma unroll
        for (int l = 0; l < 8; ++l){
          #pragma unroll
          for (int mt = 0; mt < 4; ++mt){
            int abm = mt*16 + id;
            h8 a = *(const h8*)(xb + (((size_t)t*64 + abm) << 8) + l*32 + quad*8);
            a0[mt] = __builtin_amdgcn_mfma_f32_16x16x32_f16(a, w0[l], a0[mt], 0,0,0);
            a1[mt] = __builtin_amdgcn_mfma_f32_16x16x32_f16(a, w1[l], a1[mt], 0,0,0);
          }
        }
      }
      // ---- wait: all L0 peers published h0[t-1]; lazy anti-overwrite credit ----
      if (tid < 128){
        while (__hip_atomic_load(stamp0 + tid*32, __ATOMIC_RELAXED, __HIP_MEMORY_SCOPE_AGENT) < t)
          __builtin_amdgcn_s_sleep(2);
      }
      if (tid < 64){
        while (credit < t - 7){
          int sa = __hip_atomic_load(stamp1 + tid*32,      __ATOMIC_RELAXED, __HIP_MEMORY_SCOPE_AGENT);
          int sb = __hip_atomic_load(stamp1 + (64+tid)*32, __ATOMIC_RELAXED, __HIP_MEMORY_SCOPE_AGENT);
          int s = sa < sb ? sa : sb;
          #pragma unroll
          for (int off = 32; off; off >>= 1){
            int s2 = __shfl_xor(s, off);
            s = s < s2 ? s : s2;
          }
          credit = s;
          if (credit < t - 7) __builtin_amdgcn_s_sleep(8);
        }
      }
      __syncthreads();
      // ---- h-part ----
      #pragma unroll
      for (int l = 0; l < 10; ++l){
        if (l >= lmin){
          #pragma unroll
          for (int mt = 0; mt < 4; ++mt){
            int abm = mt*16 + id;
            h8 a = aload16(hA + ((size_t)abm << 10) + (hko + l*32) + quad*8);
            a0[mt] = __builtin_amdgcn_mfma_f32_16x16x32_f16(a, w0[l], a0[mt], 0,0,0);
            a1[mt] = __builtin_amdgcn_mfma_f32_16x16x32_f16(a, w1[l], a1[mt], 0,0,0);
          }
        }
      }
      // ---- exchange: D lane(id,quad) reg r -> batch mt*16+quad*4+r, row f*16+id ----
      #pragma unroll
      for (int mt = 0; mt < 4; ++mt){
        *(f32x4*)&Gs[wave][id][mt*16 + quad*4]      = a0[mt];
        *(f32x4*)&Gs[wave][16 + id][mt*16 + quad*4] = a1[mt];
      }
      __syncthreads();
      // ---- cell phase: 2 cells (batch cb, j = j0 + jq*2 + jj) ----
      ushort2 hb; float2 hf;
      #pragma unroll
      for (int jj = 0; jj < 2; ++jj){
        int jl = jq*2 + jj;
        float p[4];
        #pragma unroll
        for (int g = 0; g < 4; ++g){
          int e = (g >> 1)*16 + (g & 1)*8 + jl;
          p[g] = Gs[0][e][cb] + Gs[1][e][cb] + Gs[2][e][cb] + Gs[3][e][cb] + bs[g][jj];
        }
        float iv = sigm(p[0]), fv = sigm(p[1]), gv = tanh_f(p[2]), ov = sigm(p[3]);
        float c = fv*c2[jj] + iv*gv;
        c2[jj] = c;
        float h = ov * tanh_f(c);
        (&hf.x)[jj] = h;
        ((u16*)&hb)[jj] = f2h(h);
      }
      union { ushort2 s; unsigned int v; } pk; pk.s = hb;
      __hip_atomic_store((unsigned int*)&hout[(size_t)cb*HH + j0 + jq*2],
                         pk.v, __ATOMIC_RELAXED, __HIP_MEMORY_SCOPE_AGENT);
      if (t == TT - 1)
        *(float2*)&hfin[(size_t)cb*HH + j0 + jq*2] = hf;
      __syncthreads();   // drains vmcnt: h-stores ack'd at coherence point
      if (tid == 0)
        __hip_atomic_store(stamp0 + jg*32, t + 1, __ATOMIC_RELAXED, __HIP_MEMORY_SCOPE_AGENT);
    }
  } else {
    // ---- preload weight fragment: 16 steps x 2 frags = 128 VGPR ----
    h8 w0[16], w1[16];
    #pragma unroll
    for (int l = 0; l < 16; ++l){
      const u16* wl = Wblk + (size_t)(wb + l)*1024 + lane*8;
      w0[l] = *(const h8*)(wl);
      w1[l] = *(const h8*)(wl + 512);
    }
    // wave w covers k [w*512, w*512+512): waves 0-1 read y0, waves 2-3 read h1
    const int koff = (wave & 1) * 512;
    for (int t = 0; t < TT; ++t){
      const u16* y0 = h0buf + ((size_t)((t + 1) & 7) << 16);  // y0[t] = h0[t]
      const u16* hA = h1buf + ((size_t)(t & 7) << 16);        // h1[t-1]
      u16* hout     = h1buf + ((size_t)((t + 1) & 7) << 16);  // h1[t]
      const u16* hsrc = (wave < 2) ? y0 : hA;
      // ---- wait: L0 published h0[t] (stamp >= t+1); L1 peers published h1[t-1] ----
      if (tid < 128){
        while (__hip_atomic_load(stamp0 + tid*32, __ATOMIC_RELAXED, __HIP_MEMORY_SCOPE_AGENT) < t + 1)
          __builtin_amdgcn_s_sleep(2);
      } else {
        while (__hip_atomic_load(stamp1 + (tid & 127)*32, __ATOMIC_RELAXED, __HIP_MEMORY_SCOPE_AGENT) < t)
          __builtin_amdgcn_s_sleep(2);
      }
      __syncthreads();
      f32x4 a0[4] = {}, a1[4] = {};
      #pragma unroll
      for (int l = 0; l < 16; ++l){
        #pragma unroll
        for (int mt = 0; mt < 4; ++mt){
          int abm = mt*16 + id;
          h8 a = aload16(hsrc + ((size_t)abm << 10) + koff + l*32 + quad*8);
          a0[mt] = __builtin_amdgcn_mfma_f32_16x16x32_f16(a, w0[l], a0[mt], 0,0,0);
          a1[mt] = __builtin_amdgcn_mfma_f32_16x16x32_f16(a, w1[l], a1[mt], 0,0,0);
        }
      }
      #pragma unroll
      for (int mt = 0; mt < 4; ++mt){
        *(f32x4*)&Gs[wave][id][mt*16 + quad*4]      = a0[mt];
        *(f32x4*)&Gs[wave][16 + id][mt*16 + quad*4] = a1[mt];
      }
      __syncthreads();
      ushort2 hb; float2 hf;
      #pragma unroll
      for (int jj = 0; jj < 2; ++jj){
        int jl = jq*2 + jj;
        float p[4];
        #pragma unroll
        for (int g = 0; g < 4; ++g){
          int e = (g >> 1)*16 + (g & 1)*8 + jl;
          p[g] = Gs[0][e][cb] + Gs[1][e][cb] + Gs[2][e][cb] + Gs[3][e][cb] + bs[g][jj];
        }
        float iv = sigm(p[0]), fv = sigm(p[1]), gv = tanh_f(p[2]), ov = sigm(p[3]);
        float c = fv*c2[jj] + iv*gv;
        c2[jj] = c;
        float h = ov * tanh_f(c);
        (&hf.x)[jj] = h;
        ((u16*)&hb)[jj] = f2h(h);
      }
      union { ushort2 s; unsigned int v; } pk; pk.s = hb;
      __hip_atomic_store((unsigned int*)&hout[(size_t)cb*HH + j0 + jq*2],
                         pk.v, __ATOMIC_RELAXED, __HIP_MEMORY_SCOPE_AGENT);
      if (t == TT - 1)
        *(float2*)&hfin[(size_t)(BB*HH) + (size_t)cb*HH + j0 + jq*2] = hf;
      __syncthreads();   // drains vmcnt: h-stores ack'd at coherence point
      if (tid == 0)
        __hip_atomic_store(stamp1 + jg*32, t + 1, __ATOMIC_RELAXED, __HIP_MEMORY_SCOPE_AGENT);
    }
  }
}

// ---------------- FC head ----------------
__global__ void fc_kernel(const float* __restrict__ hfin, const float* __restrict__ fcw,
                          const float* __restrict__ fcb, float* __restrict__ out){
  int row = blockIdx.x;          // 0..127  (0..63 layer0 hT, 64..127 layer1 hT)
  int lane = threadIdx.x;        // 64
  const float* h = hfin + (size_t)row*HH;
  float a0 = 0.f, a1 = 0.f;
  for (int j = lane; j < HH; j += 64){
    float v = h[j]; v = v > 0.f ? v : 0.f;
    a0 += v * fcw[j];
    a1 += v * fcw[HH + j];
  }
  for (int off = 32; off; off >>= 1){ a0 += __shfl_down(a0, off); a1 += __shfl_down(a1, off); }
  if (lane == 0){
    out[row*2 + 0] = 1.f/(1.f + __expf(-(a0 + fcb[0])));
    out[row*2 + 1] = 1.f/(1.f + __expf(-(a1 + fcb[1])));
  }
}

// ---------------- launch ----------------
extern "C" void kernel_launch(void* const* d_in, const int* in_sizes, int n_in,
                              void* d_out, int out_size, void* d_ws, size_t ws_size,
                              hipStream_t stream){
  (void)in_sizes; (void)n_in; (void)out_size; (void)ws_size;
  const float* x    = (const float*)d_in[0];
  const float* Wih0 = (const float*)d_in[1];
  const float* Whh0 = (const float*)d_in[2];
  const float* bih0 = (const float*)d_in[3];
  const float* bhh0 = (const float*)d_in[4];
  const float* Wih1 = (const float*)d_in[5];
  const float* Whh1 = (const float*)d_in[6];
  const float* bih1 = (const float*)d_in[7];
  const float* bhh1 = (const float*)d_in[8];
  const float* fcw  = (const float*)d_in[9];
  const float* fcb  = (const float*)d_in[10];

  char* w = (char*)d_ws;
  size_t off = 0;
  auto take = [&](size_t bytes)->char*{
    char* p = w + off; off += (bytes + 255) & ~(size_t)255; return p;
  };
  u16*   xb    = (u16*)  take((size_t)TT*BB*II*2);       // 16 MB
  u16*   wsw0  = (u16*)  take((size_t)G4*1280*2);        // 10 MB  (K=256+1024)
  u16*   wsw1  = (u16*)  take((size_t)G4*2048*2);        // 16 MB  (K=1024+1024)
  float* bias0 = (float*)take(G4*4);
  float* bias1 = (float*)take(G4*4);
  u16*   h0buf = (u16*)  take(8*(size_t)BB*HH*2);        // 1 MB ring (8 slots)
  u16*   h1buf = (u16*)  take(8*(size_t)BB*HH*2);
  float* hfin  = (float*)take(2*(size_t)BB*HH*4);        // 512 KB
  int*   stamp0= (int*)  take(128*128);                  // 128 slots x 128B
  int*   stamp1= (int*)  take(128*128);

  hipMemsetAsync(h0buf, 0, 8*(size_t)BB*HH*2, stream);
  hipMemsetAsync(h1buf, 0, 8*(size_t)BB*HH*2, stream);
  hipMemsetAsync(stamp0, 0, 128*128, stream);
  hipMemsetAsync(stamp1, 0, 128*128, stream);

  bias_comb_kernel<<<16, 256, 0, stream>>>(bih0, bhh0, bias0, G4);
  bias_comb_kernel<<<16, 256, 0, stream>>>(bih1, bhh1, bias1, G4);
  xconv_kernel<<<TT*BB, 64, 0, stream>>>(x, xb);
  // L0: 128*40*2*64/256 = 2560 blocks; L1: 128*64*2*64/256 = 4096 blocks
  wswz_kernel<<<2560, 256, 0, stream>>>(Wih0, II, Whh0, HH, wsw0, 40);
  wswz_kernel<<<4096, 256, 0, stream>>>(Wih1, HH, Whh1, HH, wsw1, 64);

  lstm_fused_kernel<<<256, 256, 0, stream>>>(xb, wsw0, wsw1, bias0, bias1,
                                             h0buf, h1buf, hfin, stamp0, stamp1);
  fc_kernel<<<2*BB, 64, 0, stream>>>(hfin, fcw, fcb, (float*)d_out);
}